// Round 1
// baseline (345.142 us; speedup 1.0000x reference)
//
#include <hip/hip_runtime.h>

typedef unsigned short u16;
typedef __attribute__((ext_vector_type(8))) unsigned short u16x8;
typedef __attribute__((ext_vector_type(4))) unsigned short u16x4;
typedef __attribute__((ext_vector_type(8))) __bf16 bf16x8;
typedef __attribute__((ext_vector_type(4))) float f32x4;

#define M_ROWS 65536   // b*s*f
#define NQKV   1536
#define KDIM   512
#define LDT    40      // padded LDS stride (bf16 elems); 40*2=80B = 16B-aligned

static __device__ __forceinline__ u16 f2bf(float f) {
  unsigned u = __builtin_bit_cast(unsigned, f);
  u += 0x7FFFu + ((u >> 16) & 1u);
  return (u16)(u >> 16);
}

static __device__ __forceinline__ f32x4 mfma_bf16(u16x8 a, u16x8 b, f32x4 c) {
  return __builtin_amdgcn_mfma_f32_16x16x32_bf16(
      __builtin_bit_cast(bf16x8, a), __builtin_bit_cast(bf16x8, b), c, 0, 0, 0);
}

// ---------------- weight transpose+convert kernels ----------------
__global__ void convW_qkv(const float* __restrict__ Wq, const float* __restrict__ Wk,
                          const float* __restrict__ Wv, u16* __restrict__ Wt) {
  int t = blockIdx.x * 256 + threadIdx.x;     // 0 .. 1536*512-1
  int n = t >> 9;
  int k = t & 511;
  const float* W = (n < 512) ? Wq : ((n < 1024) ? Wk : Wv);
  int col = n & 511;
  Wt[t] = f2bf(W[k * 512 + col]);             // Wt[n][k] = W[k][n]
}

__global__ void convWo(const float* __restrict__ Wo, u16* __restrict__ Wt) {
  int t = blockIdx.x * 256 + threadIdx.x;     // 0 .. 512*512-1
  int n = t >> 9;
  int k = t & 511;
  Wt[t] = f2bf(Wo[k * 512 + n]);
}

// ---------------- GEMM: C[M][N] = A[M][K] * Bt[N][K]^T ----------------
// AF32: A is fp32 (convert to bf16 during staging); else A is bf16 (u16)
// CF32: C is fp32 with bias add; else C is bf16 (u16), no bias
template <bool AF32, bool CF32>
__global__ __launch_bounds__(256, 2)
void gemm_kernel(const void* __restrict__ Ap, const u16* __restrict__ Bt,
                 void* __restrict__ Cp, const float* __restrict__ bias,
                 int N, int K, int n_tiles) {
  __shared__ __attribute__((aligned(16))) u16 As[128 * LDT];
  __shared__ __attribute__((aligned(16))) u16 Bs[128 * LDT];

  const int tid  = threadIdx.x;
  const int lane = tid & 63;
  const int wv   = tid >> 6;
  const int wm   = wv >> 1, wn = wv & 1;
  const int lg   = lane >> 4;       // 0..3 lane group
  const int lc   = lane & 15;

  // XCD-aware swizzle (nwg % 8 == 0 for both GEMMs)
  const int nwg  = gridDim.x;
  const int cpx  = nwg >> 3;
  const int flat = blockIdx.x;
  const int swz  = (flat & 7) * cpx + (flat >> 3);
  const int mt   = swz / n_tiles;
  const int nt   = swz % n_tiles;
  const int row0 = mt * 128, col0 = nt * 128;

  f32x4 areg[4];     // fp32 A staging (AF32)
  u16x8 areg16[2];   // bf16 A staging
  u16x8 breg[2];

  auto load_tile = [&](int kt) {
    const int k0 = kt * 32;
    if constexpr (AF32) {
      const float* A = (const float*)Ap;
#pragma unroll
      for (int p = 0; p < 4; ++p) {
        int m = (tid >> 3) + 32 * p;
        areg[p] = *(const f32x4*)(A + (size_t)(row0 + m) * K + k0 + (tid & 7) * 4);
      }
    } else {
      const u16* A = (const u16*)Ap;
#pragma unroll
      for (int p = 0; p < 2; ++p) {
        int idx = tid + 256 * p;
        areg16[p] = *(const u16x8*)(A + (size_t)(row0 + (idx >> 2)) * K + k0 + (idx & 3) * 8);
      }
    }
#pragma unroll
    for (int p = 0; p < 2; ++p) {
      int idx = tid + 256 * p;
      breg[p] = *(const u16x8*)(Bt + (size_t)(col0 + (idx >> 2)) * K + k0 + (idx & 3) * 8);
    }
  };

  auto store_tile = [&]() {
    if constexpr (AF32) {
#pragma unroll
      for (int p = 0; p < 4; ++p) {
        int m = (tid >> 3) + 32 * p;
        u16x4 w;
#pragma unroll
        for (int e = 0; e < 4; ++e) w[e] = f2bf(areg[p][e]);
        *(u16x4*)&As[m * LDT + (tid & 7) * 4] = w;
      }
    } else {
#pragma unroll
      for (int p = 0; p < 2; ++p) {
        int idx = tid + 256 * p;
        *(u16x8*)&As[(idx >> 2) * LDT + (idx & 3) * 8] = areg16[p];
      }
    }
#pragma unroll
    for (int p = 0; p < 2; ++p) {
      int idx = tid + 256 * p;
      *(u16x8*)&Bs[(idx >> 2) * LDT + (idx & 3) * 8] = breg[p];
    }
  };

  f32x4 acc[4][4];
#pragma unroll
  for (int mi = 0; mi < 4; ++mi)
#pragma unroll
    for (int ni = 0; ni < 4; ++ni) acc[mi][ni] = (f32x4){0.f, 0.f, 0.f, 0.f};

  const int nkt = K >> 5;
  load_tile(0);
  store_tile();
  __syncthreads();

  for (int kt = 0; kt < nkt; ++kt) {
    if (kt + 1 < nkt) load_tile(kt + 1);   // prefetch into regs; latency hides under MFMA

    u16x8 af[4], bfr[4];
#pragma unroll
    for (int mi = 0; mi < 4; ++mi)
      af[mi] = *(const u16x8*)&As[(wm * 64 + mi * 16 + lc) * LDT + lg * 8];
#pragma unroll
    for (int ni = 0; ni < 4; ++ni)
      bfr[ni] = *(const u16x8*)&Bs[(wn * 64 + ni * 16 + lc) * LDT + lg * 8];
#pragma unroll
    for (int mi = 0; mi < 4; ++mi)
#pragma unroll
      for (int ni = 0; ni < 4; ++ni)
        acc[mi][ni] = mfma_bf16(af[mi], bfr[ni], acc[mi][ni]);

    __syncthreads();
    if (kt + 1 < nkt) store_tile();
    __syncthreads();
  }

  // epilogue
  const int gmb = row0 + wm * 64;
  const int gnb = col0 + wn * 64;
#pragma unroll
  for (int mi = 0; mi < 4; ++mi)
#pragma unroll
    for (int ni = 0; ni < 4; ++ni) {
      const int gm = gmb + mi * 16 + lg * 4;
      const int gn = gnb + ni * 16 + lc;
      f32x4 v = acc[mi][ni];
      if constexpr (CF32) {
        float* C = (float*)Cp;
        float bv = bias[gn];
#pragma unroll
        for (int r = 0; r < 4; ++r) C[(size_t)(gm + r) * N + gn] = v[r] + bv;
      } else {
        u16* C = (u16*)Cp;
#pragma unroll
        for (int r = 0; r < 4; ++r) C[(size_t)(gm + r) * N + gn] = f2bf(v[r]);
      }
    }
}

// ---------------- attention over frames (f=16) ----------------
// qkv: [65536][1536] bf16 (cols: q 0..511 | k 512..1023 | v 1024..1535)
// one block per (b*s) token; wave wv handles heads 2*wv, 2*wv+1
__global__ __launch_bounds__(256, 4)
void attn_kernel(const u16* __restrict__ qkv, const float* __restrict__ pos_bias,
                 u16* __restrict__ attn) {
  __shared__ __attribute__((aligned(16))) u16 P_lds[4 * 256];
  const int tid  = threadIdx.x;
  const int lane = tid & 63;
  const int wv   = tid >> 6;
  const int bs   = blockIdx.x;
  const int lg   = lane >> 4;   // 0..3
  const int lc   = lane & 15;
  const float scale = 0.125f;   // 1/sqrt(64)
  const f32x4 zf = {0.f, 0.f, 0.f, 0.f};

  for (int hh = 0; hh < 2; ++hh) {
    const int h = wv * 2 + hh;
    const size_t rowb = (size_t)(bs * 16 + lc) * NQKV;

    // QK^T: A = q (row=lc), B = k^T (col=lc), K-dim = d (64 = 2 MFMAs)
    u16x8 aq0 = *(const u16x8*)(qkv + rowb + h * 64 + 0 * 32 + lg * 8);
    u16x8 aq1 = *(const u16x8*)(qkv + rowb + h * 64 + 1 * 32 + lg * 8);
    u16x8 bk0 = *(const u16x8*)(qkv + rowb + 512 + h * 64 + 0 * 32 + lg * 8);
    u16x8 bk1 = *(const u16x8*)(qkv + rowb + 512 + h * 64 + 1 * 32 + lg * 8);
    f32x4 s = mfma_bf16(aq0, bk0, zf);
    s = mfma_bf16(aq1, bk1, s);

    // bias + causal mask + softmax (rows spread over 16-lane groups)
#pragma unroll
    for (int r = 0; r < 4; ++r) {
      const int i = lg * 4 + r;
      float sv = s[r] * scale + pos_bias[h * 256 + i * 16 + lc];
      if (lc > i) sv = -1e30f;
      float m = sv;
#pragma unroll
      for (int off = 8; off >= 1; off >>= 1) m = fmaxf(m, __shfl_xor(m, off));
      float e = __expf(sv - m);
      float sm = e;
#pragma unroll
      for (int off = 8; off >= 1; off >>= 1) sm += __shfl_xor(sm, off);
      P_lds[wv * 256 + i * 16 + lc] = f2bf(e / sm);
    }
    asm volatile("s_waitcnt lgkmcnt(0)" ::: "memory");

    // PV: A = P (16x16, zero-padded to K=32), B = v
    u16x8 ap = {0, 0, 0, 0, 0, 0, 0, 0};
    if (lane < 32) ap = *(const u16x8*)&P_lds[wv * 256 + lc * 16 + lg * 8];

#pragma unroll
    for (int nd = 0; nd < 4; ++nd) {
      u16x8 bv = {0, 0, 0, 0, 0, 0, 0, 0};
      if (lane < 32) {
#pragma unroll
        for (int jj = 0; jj < 8; ++jj) {
          int j = lg * 8 + jj;   // lg in {0,1} -> j in 0..15
          bv[jj] = qkv[(size_t)(bs * 16 + j) * NQKV + 1024 + h * 64 + nd * 16 + lc];
        }
      }
      f32x4 o = mfma_bf16(ap, bv, zf);
#pragma unroll
      for (int r = 0; r < 4; ++r) {
        const int i = lg * 4 + r;
        attn[(size_t)(bs * 16 + i) * 512 + h * 64 + nd * 16 + lc] = f2bf(o[r]);
      }
    }
  }
}

// ---------------- launch ----------------
extern "C" void kernel_launch(void* const* d_in, const int* in_sizes, int n_in,
                              void* d_out, int out_size, void* d_ws, size_t ws_size,
                              hipStream_t stream) {
  const float* x        = (const float*)d_in[0];
  const float* pos_bias = (const float*)d_in[1];
  const float* Wq       = (const float*)d_in[2];
  const float* Wk       = (const float*)d_in[3];
  const float* Wv       = (const float*)d_in[4];
  const float* Wo       = (const float*)d_in[5];
  const float* bo       = (const float*)d_in[6];
  float* out            = (float*)d_out;

  u16* qkv    = (u16*)d_ws;                          // [65536][1536] bf16 (192 MiB)
  u16* attn   = qkv + (size_t)M_ROWS * NQKV;         // [65536][512]  bf16 (64 MiB)
  u16* Wqkv_t = attn;                                // [1536][512] bf16, lives in attn region until attn_kernel
  u16* Wo_t   = qkv;                                 // [512][512] bf16, lives in qkv region after attention

  // 1) Wq|Wk|Wv -> Wt[1536][512] bf16 (into attn region; GEMM1 only reads it)
  convW_qkv<<<dim3(3072), dim3(256), 0, stream>>>(Wq, Wk, Wv, Wqkv_t);

  // 2) qkv = x @ Wqkv   (M=65536, N=1536, K=512), A fp32 -> bf16 staged
  gemm_kernel<true, false><<<dim3(512 * 12), dim3(256), 0, stream>>>(
      (const void*)x, Wqkv_t, (void*)qkv, (const float*)nullptr, NQKV, KDIM, 12);

  // 3) attention over frames -> attn[65536][512] bf16 (clobbers Wqkv_t: ok)
  attn_kernel<<<dim3(4096), dim3(256), 0, stream>>>(qkv, pos_bias, attn);

  // 4) Wo -> Wo_t[512][512] bf16 (into now-dead qkv region)
  convWo<<<dim3(1024), dim3(256), 0, stream>>>(Wo, Wo_t);

  // 5) out = attn @ Wo + bo   (M=65536, N=512, K=512), fp32 epilogue
  gemm_kernel<false, true><<<dim3(512 * 4), dim3(256), 0, stream>>>(
      (const void*)attn, Wo_t, (void*)out, bo, 512, KDIM, 4);
}

// Round 2
// 306.635 us; speedup vs baseline: 1.1256x; 1.1256x over previous
//
#include <hip/hip_runtime.h>

typedef unsigned short u16;
typedef __attribute__((ext_vector_type(8))) unsigned short u16x8;
typedef __attribute__((ext_vector_type(8))) __bf16 bf16x8;
typedef __attribute__((ext_vector_type(4))) float f32x4;

#define M_ROWS 65536   // b*s*f
#define NQKV   1536
#define KDIM   512

typedef __attribute__((address_space(1))) const void gconst_void;
typedef __attribute__((address_space(3))) void lds_void;

static __device__ __forceinline__ u16 f2bf(float f) {
  unsigned u = __builtin_bit_cast(unsigned, f);
  u += 0x7FFFu + ((u >> 16) & 1u);
  return (u16)(u >> 16);
}

static __device__ __forceinline__ f32x4 mfma_bf16(u16x8 a, u16x8 b, f32x4 c) {
  return __builtin_amdgcn_mfma_f32_16x16x32_bf16(
      __builtin_bit_cast(bf16x8, a), __builtin_bit_cast(bf16x8, b), c, 0, 0, 0);
}

// ---------------- fp32 -> bf16 convert (x) ----------------
__global__ void conv_x(const float* __restrict__ x, u16* __restrict__ xb) {
  const size_t t = (size_t)blockIdx.x * 256 + threadIdx.x;  // 8 elems/thread
  f32x4 a = *(const f32x4*)(x + t * 8);
  f32x4 b = *(const f32x4*)(x + t * 8 + 4);
  u16x8 w;
#pragma unroll
  for (int e = 0; e < 4; ++e) { w[e] = f2bf(a[e]); w[e + 4] = f2bf(b[e]); }
  *(u16x8*)(xb + t * 8) = w;
}

// ---------------- weight transpose+convert ----------------
__global__ void convW_qkv(const float* __restrict__ Wq, const float* __restrict__ Wk,
                          const float* __restrict__ Wv, u16* __restrict__ Wt) {
  int t = blockIdx.x * 256 + threadIdx.x;     // 0 .. 1536*512-1
  int n = t >> 9;
  int k = t & 511;
  const float* W = (n < 512) ? Wq : ((n < 1024) ? Wk : Wv);
  int col = n & 511;
  Wt[t] = f2bf(W[k * 512 + col]);             // Wt[n][k] = W[k][n]
}

__global__ void convWo(const float* __restrict__ Wo, u16* __restrict__ Wt) {
  int t = blockIdx.x * 256 + threadIdx.x;     // 0 .. 512*512-1
  int n = t >> 9;
  int k = t & 511;
  Wt[t] = f2bf(Wo[k * 512 + n]);
}

// ---------------- GEMM: C[M][N] = A[M][K] * Bt[N][K]^T ----------------
// m97 structure: global_load_lds width-16 into linear [128][32] bf16 LDS,
// double-buffered, one __syncthreads per K-step (drains vmcnt+lgkm).
// CF32: fp32 output with bias; else bf16 output, no bias.
template <bool CF32>
__global__ __launch_bounds__(256, 3)
void gemm_bf16(const u16* __restrict__ A, const u16* __restrict__ Bt,
               void* __restrict__ Cp, const float* __restrict__ bias,
               int N, int K, int n_tiles) {
  __shared__ __attribute__((aligned(16))) u16 As[2][128 * 32];
  __shared__ __attribute__((aligned(16))) u16 Bs[2][128 * 32];

  const int tid  = threadIdx.x;
  const int lane = tid & 63;
  const int wv   = tid >> 6;
  const int wm   = wv >> 1, wn = wv & 1;
  const int lg   = lane >> 4;       // 0..3
  const int lc   = lane & 15;

  // XCD-aware swizzle (nwg % 8 == 0 for both GEMMs)
  const int nwg  = gridDim.x;
  const int cpx  = nwg >> 3;
  const int flat = blockIdx.x;
  const int swz  = (flat & 7) * cpx + (flat >> 3);
  const int mt   = swz / n_tiles;
  const int nt   = swz % n_tiles;
  const int row0 = mt * 128, col0 = nt * 128;

  // staging geometry: wave wv stages segments {2*wv, 2*wv+1}; each segment =
  // 16 rows x 32 cols = 1KB; lane l -> row l/4, col (l%4)*8 (16B). HW writes
  // LDS at wave-uniform base + lane*16 -> element s*512 + l*8 == row-major.
  const int seg = wv * 2;
  const int rA  = lane >> 2;
  const int cA  = (lane & 3) * 8;

  auto stage = [&](int buf, int kt) {
    const int k0 = kt * 32;
#pragma unroll
    for (int p = 0; p < 2; ++p) {
      const int s = seg + p;
      const u16* ga = A  + (size_t)(row0 + s * 16 + rA) * K + k0 + cA;
      const u16* gb = Bt + (size_t)(col0 + s * 16 + rA) * K + k0 + cA;
      __builtin_amdgcn_global_load_lds((gconst_void*)ga, (lds_void*)&As[buf][s * 512], 16, 0, 0);
      __builtin_amdgcn_global_load_lds((gconst_void*)gb, (lds_void*)&Bs[buf][s * 512], 16, 0, 0);
    }
  };

  f32x4 acc[4][4];
#pragma unroll
  for (int mi = 0; mi < 4; ++mi)
#pragma unroll
    for (int ni = 0; ni < 4; ++ni) acc[mi][ni] = (f32x4){0.f, 0.f, 0.f, 0.f};

  const int nkt = K >> 5;   // 16
  stage(0, 0);
  __syncthreads();

  int cur = 0;
  for (int kt = 0; kt < nkt; ++kt) {
    if (kt + 1 < nkt) stage(cur ^ 1, kt + 1);   // in-flight across ds_read+MFMA

    u16x8 af[4], bfr[4];
#pragma unroll
    for (int mi = 0; mi < 4; ++mi)
      af[mi] = *(const u16x8*)&As[cur][(wm * 64 + mi * 16 + lc) * 32 + lg * 8];
#pragma unroll
    for (int ni = 0; ni < 4; ++ni)
      bfr[ni] = *(const u16x8*)&Bs[cur][(wn * 64 + ni * 16 + lc) * 32 + lg * 8];
#pragma unroll
    for (int mi = 0; mi < 4; ++mi)
#pragma unroll
      for (int ni = 0; ni < 4; ++ni)
        acc[mi][ni] = mfma_bf16(af[mi], bfr[ni], acc[mi][ni]);

    __syncthreads();   // drains vmcnt(0) (staging) + lgkm, then barrier
    cur ^= 1;
  }

  // epilogue
  const int gmb = row0 + wm * 64;
  const int gnb = col0 + wn * 64;
#pragma unroll
  for (int mi = 0; mi < 4; ++mi)
#pragma unroll
    for (int ni = 0; ni < 4; ++ni) {
      const int gm = gmb + mi * 16 + lg * 4;
      const int gn = gnb + ni * 16 + lc;
      f32x4 v = acc[mi][ni];
      if constexpr (CF32) {
        float* C = (float*)Cp;
        float bv = bias[gn];
#pragma unroll
        for (int r = 0; r < 4; ++r) C[(size_t)(gm + r) * N + gn] = v[r] + bv;
      } else {
        u16* C = (u16*)Cp;
#pragma unroll
        for (int r = 0; r < 4; ++r) C[(size_t)(gm + r) * N + gn] = f2bf(v[r]);
      }
    }
}

// ---------------- attention over frames (f=16) ----------------
__global__ __launch_bounds__(256, 4)
void attn_kernel(const u16* __restrict__ qkv, const float* __restrict__ pos_bias,
                 u16* __restrict__ attn) {
  __shared__ __attribute__((aligned(16))) u16 P_lds[4 * 256];
  const int tid  = threadIdx.x;
  const int lane = tid & 63;
  const int wv   = tid >> 6;
  const int bs   = blockIdx.x;
  const int lg   = lane >> 4;
  const int lc   = lane & 15;
  const float scale = 0.125f;   // 1/sqrt(64)
  const f32x4 zf = {0.f, 0.f, 0.f, 0.f};

  for (int hh = 0; hh < 2; ++hh) {
    const int h = wv * 2 + hh;
    const size_t rowb = (size_t)(bs * 16 + lc) * NQKV;

    u16x8 aq0 = *(const u16x8*)(qkv + rowb + h * 64 + 0 * 32 + lg * 8);
    u16x8 aq1 = *(const u16x8*)(qkv + rowb + h * 64 + 1 * 32 + lg * 8);
    u16x8 bk0 = *(const u16x8*)(qkv + rowb + 512 + h * 64 + 0 * 32 + lg * 8);
    u16x8 bk1 = *(const u16x8*)(qkv + rowb + 512 + h * 64 + 1 * 32 + lg * 8);
    f32x4 s = mfma_bf16(aq0, bk0, zf);
    s = mfma_bf16(aq1, bk1, s);

#pragma unroll
    for (int r = 0; r < 4; ++r) {
      const int i = lg * 4 + r;
      float sv = s[r] * scale + pos_bias[h * 256 + i * 16 + lc];
      if (lc > i) sv = -1e30f;
      float m = sv;
#pragma unroll
      for (int off = 8; off >= 1; off >>= 1) m = fmaxf(m, __shfl_xor(m, off));
      float e = __expf(sv - m);
      float sm = e;
#pragma unroll
      for (int off = 8; off >= 1; off >>= 1) sm += __shfl_xor(sm, off);
      P_lds[wv * 256 + i * 16 + lc] = f2bf(e / sm);
    }
    asm volatile("s_waitcnt lgkmcnt(0)" ::: "memory");

    u16x8 ap = {0, 0, 0, 0, 0, 0, 0, 0};
    if (lane < 32) ap = *(const u16x8*)&P_lds[wv * 256 + lc * 16 + lg * 8];

#pragma unroll
    for (int nd = 0; nd < 4; ++nd) {
      u16x8 bv = {0, 0, 0, 0, 0, 0, 0, 0};
      if (lane < 32) {
#pragma unroll
        for (int jj = 0; jj < 8; ++jj) {
          int j = lg * 8 + jj;
          bv[jj] = qkv[(size_t)(bs * 16 + j) * NQKV + 1024 + h * 64 + nd * 16 + lc];
        }
      }
      f32x4 o = mfma_bf16(ap, bv, zf);
#pragma unroll
      for (int r = 0; r < 4; ++r) {
        const int i = lg * 4 + r;
        attn[(size_t)(bs * 16 + i) * 512 + h * 64 + nd * 16 + lc] = f2bf(o[r]);
      }
    }
  }
}

// ---------------- launch ----------------
extern "C" void kernel_launch(void* const* d_in, const int* in_sizes, int n_in,
                              void* d_out, int out_size, void* d_ws, size_t ws_size,
                              hipStream_t stream) {
  const float* x        = (const float*)d_in[0];
  const float* pos_bias = (const float*)d_in[1];
  const float* Wq       = (const float*)d_in[2];
  const float* Wk       = (const float*)d_in[3];
  const float* Wv       = (const float*)d_in[4];
  const float* Wo       = (const float*)d_in[5];
  const float* bo       = (const float*)d_in[6];
  float* out            = (float*)d_out;

  // ws layout (256 MiB budget):
  //   [0,   64 MiB): xb (bf16 x) -> later reused as attnbuf (xb dead after GEMM1)
  //   [64, 256 MiB): qkv (bf16)  -> later reused for Wo_t (qkv dead after attn)
  // Wqkv_t (1.5 MiB) lives in d_out, which GEMM2 fully overwrites at the end.
  u16* xb      = (u16*)d_ws;                           // [65536][512]
  u16* qkv     = xb + (size_t)M_ROWS * 512;            // [65536][1536]
  u16* attnbuf = xb;                                   // [65536][512]
  u16* Wqkv_t  = (u16*)d_out;                          // [1536][512]
  u16* Wo_t    = qkv;                                  // [512][512]

  // 1) x -> bf16
  conv_x<<<dim3(M_ROWS * KDIM / (256 * 8)), dim3(256), 0, stream>>>(x, xb);

  // 2) Wq|Wk|Wv -> Wqkv_t[1536][512] bf16 (in d_out)
  convW_qkv<<<dim3(3072), dim3(256), 0, stream>>>(Wq, Wk, Wv, Wqkv_t);

  // 3) qkv = xb @ Wqkv  (M=65536, N=1536, K=512)
  gemm_bf16<false><<<dim3(512 * 12), dim3(256), 0, stream>>>(
      xb, Wqkv_t, (void*)qkv, (const float*)nullptr, NQKV, KDIM, 12);

  // 4) attention -> attnbuf (overwrites xb: dead)
  attn_kernel<<<dim3(4096), dim3(256), 0, stream>>>(qkv, pos_bias, attnbuf);

  // 5) Wo -> Wo_t (in dead qkv region)
  convWo<<<dim3(1024), dim3(256), 0, stream>>>(Wo, Wo_t);

  // 6) out = attnbuf @ Wo + bo  (M=65536, N=512, K=512), overwrites Wqkv_t scratch
  gemm_bf16<true><<<dim3(512 * 4), dim3(256), 0, stream>>>(
      attnbuf, Wo_t, (void*)out, bo, 512, KDIM, 4);
}

// Round 3
// 285.445 us; speedup vs baseline: 1.2091x; 1.0742x over previous
//
#include <hip/hip_runtime.h>

typedef unsigned short u16;
typedef __attribute__((ext_vector_type(8))) unsigned short u16x8;
typedef __attribute__((ext_vector_type(8))) __bf16 bf16x8;
typedef __attribute__((ext_vector_type(4))) float f32x4;

#define M_ROWS 65536   // b*s*f
#define NQKV   1536
#define KDIM   512

typedef __attribute__((address_space(1))) const void gconst_void;
typedef __attribute__((address_space(3))) void lds_void;

static __device__ __forceinline__ u16 f2bf(float f) {
  unsigned u = __builtin_bit_cast(unsigned, f);
  u += 0x7FFFu + ((u >> 16) & 1u);
  return (u16)(u >> 16);
}

static __device__ __forceinline__ f32x4 mfma_bf16(u16x8 a, u16x8 b, f32x4 c) {
  return __builtin_amdgcn_mfma_f32_16x16x32_bf16(
      __builtin_bit_cast(bf16x8, a), __builtin_bit_cast(bf16x8, b), c, 0, 0, 0);
}

// ---------------- fp32 -> bf16 convert (x) ----------------
__global__ void conv_x(const float* __restrict__ x, u16* __restrict__ xb) {
  const size_t t = (size_t)blockIdx.x * 256 + threadIdx.x;  // 8 elems/thread
  f32x4 a = *(const f32x4*)(x + t * 8);
  f32x4 b = *(const f32x4*)(x + t * 8 + 4);
  u16x8 w;
#pragma unroll
  for (int e = 0; e < 4; ++e) { w[e] = f2bf(a[e]); w[e + 4] = f2bf(b[e]); }
  *(u16x8*)(xb + t * 8) = w;
}

// ---------------- weight transpose+convert ----------------
__global__ void convW_qkv(const float* __restrict__ Wq, const float* __restrict__ Wk,
                          const float* __restrict__ Wv, u16* __restrict__ Wt) {
  int t = blockIdx.x * 256 + threadIdx.x;     // 0 .. 1536*512-1
  int n = t >> 9;
  int k = t & 511;
  const float* W = (n < 512) ? Wq : ((n < 1024) ? Wk : Wv);
  int col = n & 511;
  Wt[t] = f2bf(W[k * 512 + col]);             // Wt[n][k] = W[k][n]
}

__global__ void convWo(const float* __restrict__ Wo, u16* __restrict__ Wt) {
  int t = blockIdx.x * 256 + threadIdx.x;     // 0 .. 512*512-1
  int n = t >> 9;
  int k = t & 511;
  Wt[t] = f2bf(Wo[k * 512 + n]);
}

// ---------------- GEMM 256x256, BK=64, 8 waves, per-phase schedule ----------
// C[M][N] = A[M][K] * Bt[N][K]^T.  T2 XOR-granule swizzle (pre-swizzled global
// source + swizzled ds_read, rule #21), T3/T4 phases with counted-early loads,
// T5 setprio, T1 XCD swizzle.  Stage of tile t+1 targets only the idle buffer
// (race-free by construction); boundary = vmcnt(0)+barrier (loads issued >=1
// phase earlier).
template <bool CF32>
__global__ __launch_bounds__(512, 2)
void gemm256(const u16* __restrict__ A, const u16* __restrict__ Bt,
             void* __restrict__ Cp, const float* __restrict__ bias,
             int N, int K, int n_tiles) {
  __shared__ __attribute__((aligned(16))) u16 smem[4][256 * 64];  // A0,A1,B0,B1

  const int tid  = threadIdx.x;
  const int lane = tid & 63;
  const int wid  = tid >> 6;        // 0..7
  const int wm   = wid >> 2;        // 0..1  (M half)
  const int wn   = wid & 3;         // 0..3  (N quarter)
  const int lg   = lane >> 4;       // 0..3
  const int lc   = lane & 15;
  const int srow = lane >> 3;       // 0..7  staging row within 8-row slab
  const int sg   = (lane & 7) ^ srow;  // pre-swizzled source granule

  // T1: XCD-aware swizzle (grid % 8 == 0 for both GEMMs)
  const int nwg  = gridDim.x;
  const int cpx  = nwg >> 3;
  const int flat = blockIdx.x;
  const int swz  = (flat & 7) * cpx + (flat >> 3);
  const int mt   = swz / n_tiles;
  const int nt   = swz % n_tiles;
  const int row0 = mt * 256, col0 = nt * 256;

  // stage phase ph of tile kt into buffer b: 2 x global_load_lds (1KB each)
  auto stagePh = [&](int ph, int b, int kt) {
    const int k0 = kt * 64;
#pragma unroll
    for (int cc = 0; cc < 2; ++cc) {
      if (ph < 2) {
        const int c2 = ph * 2 + cc;                 // A slab 0..3
        const int rl = wid * 32 + c2 * 8;           // wave-uniform LDS row base
        const u16* src = A + (size_t)(row0 + rl + srow) * K + k0 + sg * 8;
        __builtin_amdgcn_global_load_lds((gconst_void*)src,
                                         (lds_void*)&smem[b][rl * 64], 16, 0, 0);
      } else {
        const int c2 = (ph - 2) * 2 + cc;           // B slab 0..3
        const int rl = wid * 32 + c2 * 8;
        const u16* src = Bt + (size_t)(col0 + rl + srow) * K + k0 + sg * 8;
        __builtin_amdgcn_global_load_lds((gconst_void*)src,
                                         (lds_void*)&smem[2 + b][rl * 64], 16, 0, 0);
      }
    }
  };

  f32x4 acc[8][4];
#pragma unroll
  for (int mi = 0; mi < 8; ++mi)
#pragma unroll
    for (int ni = 0; ni < 4; ++ni) acc[mi][ni] = (f32x4){0.f, 0.f, 0.f, 0.f};

  const int nkt = K >> 6;   // 8

  // prologue: stage tile 0 into buf 0
#pragma unroll
  for (int ph = 0; ph < 4; ++ph) stagePh(ph, 0, 0);
  asm volatile("s_waitcnt vmcnt(0)" ::: "memory");
  __builtin_amdgcn_s_barrier();

  for (int t = 0; t < nkt; ++t) {
    const int  c   = t & 1;
    const bool pre = (t + 1) < nkt;
    const u16* Asb = &smem[c][0];
    const u16* Bsb = &smem[2 + c][0];
    u16x8 af[4], bfr[4];

#pragma unroll
    for (int ph = 0; ph < 4; ++ph) {
      const int ks = ph >> 1;   // k-slice 0/1
      const int mh = ph & 1;    // M-half of wave tile
      const int gsw = ((ks * 4 + lg) ^ (lc & 7)) << 3;  // swizzled granule (elems)
      if (mh == 0) {
#pragma unroll
        for (int ni = 0; ni < 4; ++ni)
          bfr[ni] = *(const u16x8*)&Bsb[(wn * 64 + ni * 16 + lc) * 64 + gsw];
      }
#pragma unroll
      for (int i = 0; i < 4; ++i)
        af[i] = *(const u16x8*)&Asb[(wm * 128 + (mh * 4 + i) * 16 + lc) * 64 + gsw];
      if (pre) stagePh(ph, c ^ 1, t + 1);

      __builtin_amdgcn_s_barrier();
      asm volatile("s_waitcnt lgkmcnt(0)" ::: "memory");
      __builtin_amdgcn_sched_barrier(0);
      __builtin_amdgcn_s_setprio(1);
#pragma unroll
      for (int i = 0; i < 4; ++i)
#pragma unroll
        for (int ni = 0; ni < 4; ++ni)
          acc[mh * 4 + i][ni] = mfma_bf16(af[i], bfr[ni], acc[mh * 4 + i][ni]);
      __builtin_amdgcn_s_setprio(0);
      __builtin_amdgcn_sched_barrier(0);
      if (ph < 3) __builtin_amdgcn_s_barrier();
    }
    // tile boundary: tile t+1's loads (issued during phases above) must land
    asm volatile("s_waitcnt vmcnt(0)" ::: "memory");
    __builtin_amdgcn_s_barrier();
  }

  // epilogue
  const int gmb = row0 + wm * 128;
  const int gnb = col0 + wn * 64;
#pragma unroll
  for (int mi = 0; mi < 8; ++mi)
#pragma unroll
    for (int ni = 0; ni < 4; ++ni) {
      const int gm = gmb + mi * 16 + lg * 4;
      const int gn = gnb + ni * 16 + lc;
      f32x4 v = acc[mi][ni];
      if constexpr (CF32) {
        float* C = (float*)Cp;
        float bv = bias[gn];
#pragma unroll
        for (int r = 0; r < 4; ++r) C[(size_t)(gm + r) * N + gn] = v[r] + bv;
      } else {
        u16* C = (u16*)Cp;
#pragma unroll
        for (int r = 0; r < 4; ++r) C[(size_t)(gm + r) * N + gn] = f2bf(v[r]);
      }
    }
}

// ---------------- attention over frames (f=16) ----------------
__global__ __launch_bounds__(256, 4)
void attn_kernel(const u16* __restrict__ qkv, const float* __restrict__ pos_bias,
                 u16* __restrict__ attn) {
  __shared__ __attribute__((aligned(16))) u16 P_lds[4 * 256];
  const int tid  = threadIdx.x;
  const int lane = tid & 63;
  const int wv   = tid >> 6;
  const int bs   = blockIdx.x;
  const int lg   = lane >> 4;
  const int lc   = lane & 15;
  const float scale = 0.125f;   // 1/sqrt(64)
  const f32x4 zf = {0.f, 0.f, 0.f, 0.f};

  for (int hh = 0; hh < 2; ++hh) {
    const int h = wv * 2 + hh;
    const size_t rowb = (size_t)(bs * 16 + lc) * NQKV;

    u16x8 aq0 = *(const u16x8*)(qkv + rowb + h * 64 + 0 * 32 + lg * 8);
    u16x8 aq1 = *(const u16x8*)(qkv + rowb + h * 64 + 1 * 32 + lg * 8);
    u16x8 bk0 = *(const u16x8*)(qkv + rowb + 512 + h * 64 + 0 * 32 + lg * 8);
    u16x8 bk1 = *(const u16x8*)(qkv + rowb + 512 + h * 64 + 1 * 32 + lg * 8);
    f32x4 s = mfma_bf16(aq0, bk0, zf);
    s = mfma_bf16(aq1, bk1, s);

#pragma unroll
    for (int r = 0; r < 4; ++r) {
      const int i = lg * 4 + r;
      float sv = s[r] * scale + pos_bias[h * 256 + i * 16 + lc];
      if (lc > i) sv = -1e30f;
      float m = sv;
#pragma unroll
      for (int off = 8; off >= 1; off >>= 1) m = fmaxf(m, __shfl_xor(m, off));
      float e = __expf(sv - m);
      float sm = e;
#pragma unroll
      for (int off = 8; off >= 1; off >>= 1) sm += __shfl_xor(sm, off);
      P_lds[wv * 256 + i * 16 + lc] = f2bf(e / sm);
    }
    asm volatile("s_waitcnt lgkmcnt(0)" ::: "memory");

    u16x8 ap = {0, 0, 0, 0, 0, 0, 0, 0};
    if (lane < 32) ap = *(const u16x8*)&P_lds[wv * 256 + lc * 16 + lg * 8];

#pragma unroll
    for (int nd = 0; nd < 4; ++nd) {
      u16x8 bv = {0, 0, 0, 0, 0, 0, 0, 0};
      if (lane < 32) {
#pragma unroll
        for (int jj = 0; jj < 8; ++jj) {
          int j = lg * 8 + jj;
          bv[jj] = qkv[(size_t)(bs * 16 + j) * NQKV + 1024 + h * 64 + nd * 16 + lc];
        }
      }
      f32x4 o = mfma_bf16(ap, bv, zf);
#pragma unroll
      for (int r = 0; r < 4; ++r) {
        const int i = lg * 4 + r;
        attn[(size_t)(bs * 16 + i) * 512 + h * 64 + nd * 16 + lc] = f2bf(o[r]);
      }
    }
  }
}

// ---------------- launch ----------------
extern "C" void kernel_launch(void* const* d_in, const int* in_sizes, int n_in,
                              void* d_out, int out_size, void* d_ws, size_t ws_size,
                              hipStream_t stream) {
  const float* x        = (const float*)d_in[0];
  const float* pos_bias = (const float*)d_in[1];
  const float* Wq       = (const float*)d_in[2];
  const float* Wk       = (const float*)d_in[3];
  const float* Wv       = (const float*)d_in[4];
  const float* Wo       = (const float*)d_in[5];
  const float* bo       = (const float*)d_in[6];
  float* out            = (float*)d_out;

  // ws layout (256 MiB budget):
  //   [0,   64 MiB): xb (bf16 x) -> reused as attnbuf after GEMM1
  //   [64, 256 MiB): qkv (bf16)  -> reused for Wo_t after attention
  // Wqkv_t (1.5 MiB) lives in d_out (fully overwritten by GEMM2 at the end).
  u16* xb      = (u16*)d_ws;                           // [65536][512]
  u16* qkv     = xb + (size_t)M_ROWS * 512;            // [65536][1536]
  u16* attnbuf = xb;                                   // [65536][512]
  u16* Wqkv_t  = (u16*)d_out;                          // [1536][512]
  u16* Wo_t    = qkv;                                  // [512][512]

  // 1) x -> bf16
  conv_x<<<dim3(M_ROWS * KDIM / (256 * 8)), dim3(256), 0, stream>>>(x, xb);

  // 2) Wq|Wk|Wv -> Wqkv_t[1536][512] bf16 (in d_out)
  convW_qkv<<<dim3(3072), dim3(256), 0, stream>>>(Wq, Wk, Wv, Wqkv_t);

  // 3) qkv = xb @ Wqkv  (M=65536, N=1536, K=512): 256x6 tiles = 1536 blocks
  gemm256<false><<<dim3(1536), dim3(512), 0, stream>>>(
      xb, Wqkv_t, (void*)qkv, (const float*)nullptr, NQKV, KDIM, 6);

  // 4) attention -> attnbuf (overwrites xb: dead)
  attn_kernel<<<dim3(4096), dim3(256), 0, stream>>>(qkv, pos_bias, attnbuf);

  // 5) Wo -> Wo_t (in dead qkv region)
  convWo<<<dim3(1024), dim3(256), 0, stream>>>(Wo, Wo_t);

  // 6) out = attnbuf @ Wo + bo  (M=65536, N=512, K=512): 256x2 tiles = 512 blocks
  gemm256<true><<<dim3(512), dim3(512), 0, stream>>>(
      attnbuf, Wo_t, (void*)out, bo, 512, KDIM, 2);
}